// Round 1
// baseline (1990.470 us; speedup 1.0000x reference)
//
#include <hip/hip_runtime.h>
#include <hip/hip_bf16.h>

// Problem constants (B,T,DIM,H,D) = (4,2048,1024,8,128)
constexpr int B_ = 4;
constexpr int T_ = 2048;
constexpr int DIM_ = 1024;
constexpr int H_ = 8;
constexpr int D_ = 128;
constexpr int HDIM_ = H_ * D_;   // 1024

// ---------------------------------------------------------------------------
// RoPE tables: cos/sin[t][j], j<32 (nonzero freqs only; j in [32,64) is identity)
// Mirrors: freq = (1/1024)^(j/31), theta = t*freq  (all f32, like the JAX ref)
// ---------------------------------------------------------------------------
__global__ void rope_tables_k(float* __restrict__ cost, float* __restrict__ sint) {
    int idx = blockIdx.x * blockDim.x + threadIdx.x;   // T_*32 entries
    if (idx >= T_ * 32) return;
    int t = idx >> 5, j = idx & 31;
    float step = 1.0f / 31.0f;             // matches jnp.linspace(0,1,32) step
    float e = (float)j * step;
    float freq = powf(1.0f / 1024.0f, e);
    float th = (float)t * freq;
    cost[idx] = cosf(th);
    sint[idx] = sinf(th);
}

// ---------------------------------------------------------------------------
// f32 GEMM, C[M,N] = A[M,K] * B[N,K]^T  (both inputs K-contiguous, "NT")
// 128x128 tile, BK=16, 256 threads, 8x8 per thread with split col/row mapping
// (tx*4 and 64+tx*4) so LDS reads are <=2-way bank aliased (free).
// M,N,K must be multiples of 128/128/16 (true for all uses here).
// ---------------------------------------------------------------------------
constexpr int GBM = 128, GBN = 128, GBK = 16;

__global__ __launch_bounds__(256) void gemm_nt_f32(
    const float* __restrict__ A, const float* __restrict__ Bm,
    float* __restrict__ C, int M, int N, int K) {
    __shared__ float As[GBK][GBM + 4];
    __shared__ float Bs[GBK][GBN + 4];
    const int tid = threadIdx.x;
    const int tx = tid & 15, ty = tid >> 4;
    const size_t m0 = (size_t)blockIdx.y * GBM;
    const size_t n0 = (size_t)blockIdx.x * GBN;

    float acc[8][8] = {};

    for (int k0 = 0; k0 < K; k0 += GBK) {
#pragma unroll
        for (int i = 0; i < 2; ++i) {
            int idx = tid + i * 256;          // 512 float4 per operand tile
            int r = idx >> 2;                 // 4 float4 per row (BK=16)
            int c4 = (idx & 3) * 4;
            float4 a = *(const float4*)&A[(m0 + r) * (size_t)K + k0 + c4];
            As[c4 + 0][r] = a.x; As[c4 + 1][r] = a.y;
            As[c4 + 2][r] = a.z; As[c4 + 3][r] = a.w;
            float4 b = *(const float4*)&Bm[(n0 + r) * (size_t)K + k0 + c4];
            Bs[c4 + 0][r] = b.x; Bs[c4 + 1][r] = b.y;
            Bs[c4 + 2][r] = b.z; Bs[c4 + 3][r] = b.w;
        }
        __syncthreads();
#pragma unroll
        for (int kk = 0; kk < GBK; ++kk) {
            float4 a0 = *(const float4*)&As[kk][ty * 4];
            float4 a1 = *(const float4*)&As[kk][64 + ty * 4];
            float4 b0 = *(const float4*)&Bs[kk][tx * 4];
            float4 b1 = *(const float4*)&Bs[kk][64 + tx * 4];
            float av[8] = {a0.x, a0.y, a0.z, a0.w, a1.x, a1.y, a1.z, a1.w};
            float bv[8] = {b0.x, b0.y, b0.z, b0.w, b1.x, b1.y, b1.z, b1.w};
#pragma unroll
            for (int i = 0; i < 8; ++i)
#pragma unroll
                for (int j = 0; j < 8; ++j)
                    acc[i][j] += av[i] * bv[j];
        }
        __syncthreads();
    }
#pragma unroll
    for (int i = 0; i < 8; ++i) {
        int r = (i < 4) ? (ty * 4 + i) : (64 + ty * 4 + (i - 4));
        float4 c0 = make_float4(acc[i][0], acc[i][1], acc[i][2], acc[i][3]);
        float4 c1 = make_float4(acc[i][4], acc[i][5], acc[i][6], acc[i][7]);
        *(float4*)&C[(m0 + r) * (size_t)N + n0 + tx * 4] = c0;
        *(float4*)&C[(m0 + r) * (size_t)N + n0 + 64 + tx * 4] = c1;
    }
}

// ---------------------------------------------------------------------------
// Pointwise prep on the qkv buffer (layout B,T,3,H,D):
//   q,k: RMS-norm over D then RoPE;  v: lambdas[0]*v + lambdas[1]*ve
// One 64-lane wave per (b,t,h); lane l owns elements l and l+64 (RoPE pair).
// ---------------------------------------------------------------------------
__global__ __launch_bounds__(256) void qkv_prep_k(
    float* __restrict__ qkv, const float* __restrict__ ve,
    const float* __restrict__ lambdas,
    const float* __restrict__ cost, const float* __restrict__ sint) {
    const int gw = (blockIdx.x * 256 + threadIdx.x) >> 6;  // global wave id
    const int lane = threadIdx.x & 63;
    const int h = gw & (H_ - 1);
    const int t = (gw / H_) & (T_ - 1);
    const int b = gw / (H_ * T_);
    const size_t rowbase = ((size_t)(b * T_ + t) * 3) * HDIM_ + (size_t)h * D_;
    const float l0 = lambdas[0], l1 = lambdas[1];
    const float c = (lane < 32) ? cost[t * 32 + lane] : 1.0f;
    const float s = (lane < 32) ? sint[t * 32 + lane] : 0.0f;
    const float EPS = 1.1920928955078125e-07f;  // float32 eps (matches jnp)

#pragma unroll
    for (int qk = 0; qk < 2; ++qk) {
        float* p = qkv + rowbase + (size_t)qk * HDIM_;
        float x1 = p[lane], x2 = p[lane + 64];
        float ss = x1 * x1 + x2 * x2;
#pragma unroll
        for (int m = 32; m >= 1; m >>= 1) ss += __shfl_xor(ss, m, 64);
        float r = 1.0f / sqrtf(ss * (1.0f / 128.0f) + EPS);
        x1 *= r; x2 *= r;
        p[lane]      = x1 * c + x2 * s;
        p[lane + 64] = x2 * c - x1 * s;
    }
    float* pv = qkv + rowbase + (size_t)2 * HDIM_;
    const float* pe = ve + (size_t)(b * T_ + t) * HDIM_ + (size_t)h * D_;
    pv[lane]      = l0 * pv[lane]      + l1 * pe[lane];
    pv[lane + 64] = l0 * pv[lane + 64] + l1 * pe[lane + 64];
}

// ---------------------------------------------------------------------------
// Causal flash attention, f32. Block = 256 threads handles one (b,h,qtile=64).
// K/V tiles of 32 staged per iteration. Q,K staged k-major (outer-product
// form). Online softmax; 16-lane shfl_xor row reductions. Heavy qtiles first.
// LDS ~76 KB -> 2 blocks/CU.
// ---------------------------------------------------------------------------
constexpr int BQ = 64, BS = 32;

__global__ __launch_bounds__(256) void attn_k(
    const float* __restrict__ qkv, float* __restrict__ y) {
    __shared__ float Qt[D_][BQ + 4];     // k-major Q
    __shared__ float Kt[D_][BS + 2];     // k-major K
    __shared__ float Vs[BS][D_ + 4];     // row-major V
    __shared__ float Pt[BS][BQ + 4];     // kv-major P

    const int tid = threadIdx.x;
    const int tx = tid & 15, ty = tid >> 4;
    const int qt = gridDim.x - 1 - blockIdx.x;   // longest-running tiles first
    const int h = blockIdx.y, b = blockIdx.z;
    const int q0 = qt * BQ;
    const float scale = 0.08838834764831845f;    // 128^-0.5

    // stage Q (rows q0..q0+63) transposed into LDS
    const size_t qbase = ((size_t)(b * T_ + q0) * 3) * HDIM_ + (size_t)h * D_;
#pragma unroll
    for (int i = 0; i < 8; ++i) {
        int idx = tid + i * 256;       // 2048 float4
        int r = idx >> 5;              // 32 float4 per row
        int d4 = (idx & 31) * 4;
        float4 v = *(const float4*)&qkv[qbase + (size_t)r * 3 * HDIM_ + d4];
        Qt[d4 + 0][r] = v.x; Qt[d4 + 1][r] = v.y;
        Qt[d4 + 2][r] = v.z; Qt[d4 + 3][r] = v.w;
    }

    float m_r[4], l_r[4], acc[4][8];
#pragma unroll
    for (int i = 0; i < 4; ++i) {
        m_r[i] = -1e30f; l_r[i] = 0.0f;
#pragma unroll
        for (int j = 0; j < 8; ++j) acc[i][j] = 0.0f;
    }

    const int nkv = q0 / BS + 2;   // causal: kv tiles [0, nkv)
    for (int sblk = 0; sblk < nkv; ++sblk) {
        const int s0 = sblk * BS;
        __syncthreads();   // protect Kt/Vs/Pt from previous iteration readers
        const size_t kbase = ((size_t)(b * T_ + s0) * 3 + 1) * HDIM_ + (size_t)h * D_;
        const size_t vbase = ((size_t)(b * T_ + s0) * 3 + 2) * HDIM_ + (size_t)h * D_;
#pragma unroll
        for (int i = 0; i < 4; ++i) {
            int idx = tid + i * 256;   // 1024 float4
            int r = idx >> 5;
            int d4 = (idx & 31) * 4;
            float4 kv4 = *(const float4*)&qkv[kbase + (size_t)r * 3 * HDIM_ + d4];
            Kt[d4 + 0][r] = kv4.x; Kt[d4 + 1][r] = kv4.y;
            Kt[d4 + 2][r] = kv4.z; Kt[d4 + 3][r] = kv4.w;
            float4 vv4 = *(const float4*)&qkv[vbase + (size_t)r * 3 * HDIM_ + d4];
            *(float4*)&Vs[r][d4] = vv4;
        }
        __syncthreads();

        // S = Q * K^T for this tile: thread owns rows ty*4..+3, cols tx*2..+1
        float sacc[4][2] = {};
#pragma unroll 16
        for (int k = 0; k < D_; ++k) {
            float4 a = *(const float4*)&Qt[k][ty * 4];
            float2 kb = *(const float2*)&Kt[k][tx * 2];
#pragma unroll
            for (int i = 0; i < 4; ++i) {
                sacc[i][0] += (&a.x)[i] * kb.x;
                sacc[i][1] += (&a.x)[i] * kb.y;
            }
        }

        const bool edge = (s0 + BS > q0);
#pragma unroll
        for (int i = 0; i < 4; ++i) {
            int qg = q0 + ty * 4 + i;
#pragma unroll
            for (int j = 0; j < 2; ++j) {
                float sv = sacc[i][j] * scale;
                int kg = s0 + tx * 2 + j;
                if (edge && kg > qg) sv = -1e9f;
                sacc[i][j] = sv;
            }
        }

        // online softmax (rows replicated across the 16 tx lanes)
#pragma unroll
        for (int i = 0; i < 4; ++i) {
            float mx = fmaxf(sacc[i][0], sacc[i][1]);
#pragma unroll
            for (int m = 8; m >= 1; m >>= 1) mx = fmaxf(mx, __shfl_xor(mx, m, 64));
            float mnew = fmaxf(m_r[i], mx);
            float sf = __expf(m_r[i] - mnew);
            m_r[i] = mnew;
            float p0 = __expf(sacc[i][0] - mnew);
            float p1 = __expf(sacc[i][1] - mnew);
            float ls = p0 + p1;
#pragma unroll
            for (int m = 8; m >= 1; m >>= 1) ls += __shfl_xor(ls, m, 64);
            l_r[i] = l_r[i] * sf + ls;
#pragma unroll
            for (int j = 0; j < 8; ++j) acc[i][j] *= sf;
            Pt[tx * 2 + 0][ty * 4 + i] = p0;
            Pt[tx * 2 + 1][ty * 4 + i] = p1;
        }
        __syncthreads();

        // acc += P * V: thread owns rows ty*4..+3, cols tx*4..+3 and 64+tx*4..+3
#pragma unroll 8
        for (int k = 0; k < BS; ++k) {
            float4 pa = *(const float4*)&Pt[k][ty * 4];
            float4 v0 = *(const float4*)&Vs[k][tx * 4];
            float4 v1 = *(const float4*)&Vs[k][64 + tx * 4];
#pragma unroll
            for (int i = 0; i < 4; ++i) {
                float p = (&pa.x)[i];
                acc[i][0] += p * v0.x; acc[i][1] += p * v0.y;
                acc[i][2] += p * v0.z; acc[i][3] += p * v0.w;
                acc[i][4] += p * v1.x; acc[i][5] += p * v1.y;
                acc[i][6] += p * v1.z; acc[i][7] += p * v1.w;
            }
        }
    }

    // epilogue: y[b, q0+row, h, :] = acc / l
#pragma unroll
    for (int i = 0; i < 4; ++i) {
        float inv = 1.0f / l_r[i];
        float4 o0 = make_float4(acc[i][0] * inv, acc[i][1] * inv,
                                acc[i][2] * inv, acc[i][3] * inv);
        float4 o1 = make_float4(acc[i][4] * inv, acc[i][5] * inv,
                                acc[i][6] * inv, acc[i][7] * inv);
        size_t yb = ((size_t)(b * T_ + q0 + ty * 4 + i)) * HDIM_ + (size_t)h * D_;
        *(float4*)&y[yb + tx * 4] = o0;
        *(float4*)&y[yb + 64 + tx * 4] = o1;
    }
}

// ---------------------------------------------------------------------------
// Launch. Workspace layout (all f32):
//   [0)                qkv   B*T*3*HDIM   (96 MB)
//   [96 MB)            y     B*T*HDIM     (32 MB)
//   [128 MB)           cos table T*32, then sin table T*32 (0.5 MB)
// Total 128.5 MB; every byte we read is written first each call.
// ---------------------------------------------------------------------------
extern "C" void kernel_launch(void* const* d_in, const int* in_sizes, int n_in,
                              void* d_out, int out_size, void* d_ws, size_t ws_size,
                              hipStream_t stream) {
    (void)in_sizes; (void)n_in; (void)out_size; (void)ws_size;
    const float* x        = (const float*)d_in[0];
    const float* ve       = (const float*)d_in[1];
    const float* qkv_w    = (const float*)d_in[2];
    const float* lambdas  = (const float*)d_in[3];
    const float* c_proj_w = (const float*)d_in[4];
    float* out = (float*)d_out;

    char* ws = (char*)d_ws;
    float* qkv  = (float*)ws;
    float* y    = (float*)(ws + (size_t)B_ * T_ * 3 * HDIM_ * sizeof(float));
    float* cost = (float*)(ws + (size_t)B_ * T_ * 4 * HDIM_ * sizeof(float));
    float* sint = cost + (size_t)T_ * 32;

    hipLaunchKernelGGL(rope_tables_k, dim3((T_ * 32 + 255) / 256), dim3(256), 0, stream,
                       cost, sint);
    hipLaunchKernelGGL(gemm_nt_f32, dim3(3 * HDIM_ / GBN, (B_ * T_) / GBM), dim3(256), 0,
                       stream, x, qkv_w, qkv, B_ * T_, 3 * HDIM_, DIM_);
    hipLaunchKernelGGL(qkv_prep_k, dim3(B_ * T_ * H_ / 4), dim3(256), 0, stream,
                       qkv, ve, lambdas, cost, sint);
    hipLaunchKernelGGL(attn_k, dim3(T_ / BQ, H_, B_), dim3(256), 0, stream, qkv, y);
    hipLaunchKernelGGL(gemm_nt_f32, dim3(DIM_ / GBN, (B_ * T_) / GBM), dim3(256), 0,
                       stream, y, c_proj_w, out, B_ * T_, DIM_, HDIM_);
}

// Round 3
// 419.686 us; speedup vs baseline: 4.7428x; 4.7428x over previous
//
#include <hip/hip_runtime.h>
#include <hip/hip_bf16.h>

constexpr int B_ = 4;
constexpr int T_ = 2048;
constexpr int DIM_ = 1024;
constexpr int H_ = 8;
constexpr int D_ = 128;
constexpr int HDIM_ = H_ * D_;   // 1024

typedef __attribute__((ext_vector_type(8))) short bf16x8;
typedef __attribute__((ext_vector_type(8))) unsigned short ushort8;
typedef __attribute__((ext_vector_type(4))) float f32x4;

#define ATTN_SCALE 0.08838834764831845f

__device__ __forceinline__ unsigned short f2bf(float x) {
    unsigned u = __float_as_uint(x);
    unsigned r = (u + 0x7FFFu + ((u >> 16) & 1u)) >> 16;
    return (unsigned short)r;
}
__device__ __forceinline__ float bf2f(unsigned short u) {
    return __uint_as_float(((unsigned)u) << 16);
}

// async 16B global -> LDS (dest: wave-uniform base + lane*16; src: per-lane)
__device__ __forceinline__ void async_ld16(void* ldsdst, const void* gsrc) {
    __builtin_amdgcn_global_load_lds(
        (const __attribute__((address_space(1))) unsigned int*)gsrc,
        (__attribute__((address_space(3))) unsigned int*)ldsdst, 16, 0, 0);
}

// ---------------------------------------------------------------------------
// f32 -> bf16 convert, 4 elems/thread
// ---------------------------------------------------------------------------
__global__ __launch_bounds__(256) void cvtk(const float* __restrict__ in,
                                            unsigned short* __restrict__ out, int n4) {
    int i = blockIdx.x * 256 + threadIdx.x;
    if (i < n4) {
        float4 v = ((const float4*)in)[i];
        ushort4 o;
        o.x = f2bf(v.x); o.y = f2bf(v.y); o.z = f2bf(v.z); o.w = f2bf(v.w);
        ((ushort4*)out)[i] = o;
    }
}

// ---------------------------------------------------------------------------
// RoPE tables (f32): cos/sin[t][j], j<32 real freqs; j>=32 identity (handled
// in prep). freq = (1/1024)^(j/31), theta = t*freq.
// ---------------------------------------------------------------------------
__global__ void rope_tables_k(float* __restrict__ cost, float* __restrict__ sint) {
    int idx = blockIdx.x * blockDim.x + threadIdx.x;
    if (idx >= T_ * 32) return;
    int t = idx >> 5, j = idx & 31;
    float e = (float)j * (1.0f / 31.0f);
    float freq = powf(1.0f / 1024.0f, e);
    float th = (float)t * freq;
    cost[idx] = cosf(th);
    sint[idx] = sinf(th);
}

// ---------------------------------------------------------------------------
// bf16 NT GEMM: C[M,N] = A[M,K] * B[N,K]^T, 128x128 tile, BK=64, 4 waves 2x2,
// each wave 64x64 out (4x4 frags of 16x16x32 MFMA). global_load_lds staging
// with pre-swizzled source; LDS[row][c] = G[row][c ^ (row&7)] (16B chunks).
// C written f32 (Cf) or bf16 (Cb) -- exactly one non-null.
// ---------------------------------------------------------------------------
__global__ __launch_bounds__(256) void gemm_bf16_nt(
    const unsigned short* __restrict__ A, const unsigned short* __restrict__ Bw,
    float* __restrict__ Cf, unsigned short* __restrict__ Cb,
    int M, int N, int K) {
    __shared__ __align__(16) unsigned short As[128 * 64];
    __shared__ __align__(16) unsigned short Bs[128 * 64];
    const int tid = threadIdx.x;
    const int l = tid & 63, w = tid >> 6;
    const int g = l >> 4, q16 = l & 15;

    // bijective XCD swizzle (nwg % 8 == 0 for all our grids)
    int nwg = gridDim.x * gridDim.y;
    int lin = blockIdx.y * gridDim.x + blockIdx.x;
    int swz = (lin & 7) * (nwg >> 3) + (lin >> 3);
    int bx = swz % gridDim.x, by = swz / gridDim.x;
    const size_t m0 = (size_t)by * 128, n0 = (size_t)bx * 128;
    const int wm = (w >> 1) * 64, wn = (w & 1) * 64;

    f32x4 acc[4][4];
#pragma unroll
    for (int i = 0; i < 4; ++i)
#pragma unroll
        for (int j = 0; j < 4; ++j) acc[i][j] = (f32x4){0.f, 0.f, 0.f, 0.f};

    const int srow = l >> 3;                   // 0..7 within 8-row group
    const int schunk = (l & 7) ^ (srow & 7);   // pre-swizzled source chunk
    const unsigned short* aBase = A + (m0 + srow) * (size_t)K + schunk * 8;
    const unsigned short* bBase = Bw + (n0 + srow) * (size_t)K + schunk * 8;
    const int roff = q16 & 7;                  // read-row swizzle key

    for (int k0 = 0; k0 < K; k0 += 64) {
#pragma unroll
        for (int i = 0; i < 4; ++i) {
            size_t rstep = (size_t)(w * 4 + i) * 8 * K;
            async_ld16(&As[(w * 4 + i) * 512], aBase + rstep + k0);
            async_ld16(&Bs[(w * 4 + i) * 512], bBase + rstep + k0);
        }
        __syncthreads();
#pragma unroll
        for (int ks = 0; ks < 2; ++ks) {
            bf16x8 af[4], bf[4];
#pragma unroll
            for (int f = 0; f < 4; ++f) {
                int off = (ks * 32 + g * 8) ^ (roff << 3);
                af[f] = *(const bf16x8*)&As[(wm + f * 16 + q16) * 64 + off];
                bf[f] = *(const bf16x8*)&Bs[(wn + f * 16 + q16) * 64 + off];
            }
#pragma unroll
            for (int fm = 0; fm < 4; ++fm)
#pragma unroll
                for (int fn = 0; fn < 4; ++fn)
                    acc[fm][fn] = __builtin_amdgcn_mfma_f32_16x16x32_bf16(
                        af[fm], bf[fn], acc[fm][fn], 0, 0, 0);
        }
        __syncthreads();
    }

    if (Cb) {
#pragma unroll
        for (int fm = 0; fm < 4; ++fm)
#pragma unroll
            for (int r = 0; r < 4; ++r) {
                size_t base = (m0 + wm + fm * 16 + 4 * g + r) * (size_t)N + n0 + wn + q16;
#pragma unroll
                for (int fn = 0; fn < 4; ++fn)
                    Cb[base + fn * 16] = f2bf(acc[fm][fn][r]);
            }
    } else {
#pragma unroll
        for (int fm = 0; fm < 4; ++fm)
#pragma unroll
            for (int r = 0; r < 4; ++r) {
                size_t base = (m0 + wm + fm * 16 + 4 * g + r) * (size_t)N + n0 + wn + q16;
#pragma unroll
                for (int fn = 0; fn < 4; ++fn)
                    Cf[base + fn * 16] = acc[fm][fn][r];
            }
    }
}

// ---------------------------------------------------------------------------
// Pointwise prep, in-place on bf16 qkv (layout B,T,3,H,D):
//   q,k: RMSNorm over D then RoPE;  v: lambdas[0]*v + lambdas[1]*ve (ve f32)
// One wave per (b,t,h); lane l owns d=l and d=l+64.
// ---------------------------------------------------------------------------
__global__ __launch_bounds__(256) void qkv_prep_k(
    unsigned short* __restrict__ qkv, const float* __restrict__ ve,
    const float* __restrict__ lambdas,
    const float* __restrict__ cost, const float* __restrict__ sint) {
    const int gw = (blockIdx.x * 256 + threadIdx.x) >> 6;
    const int lane = threadIdx.x & 63;
    const int h = gw & (H_ - 1);
    const int t = (gw / H_) & (T_ - 1);
    const int b = gw / (H_ * T_);
    const size_t rowbase = ((size_t)(b * T_ + t) * 3) * HDIM_ + (size_t)h * D_;
    const float l0 = lambdas[0], l1 = lambdas[1];
    const float c = (lane < 32) ? cost[t * 32 + lane] : 1.0f;
    const float s = (lane < 32) ? sint[t * 32 + lane] : 0.0f;
    const float EPS = 1.1920928955078125e-07f;

#pragma unroll
    for (int qk = 0; qk < 2; ++qk) {
        unsigned short* p = qkv + rowbase + (size_t)qk * HDIM_;
        float x1 = bf2f(p[lane]), x2 = bf2f(p[lane + 64]);
        float ss = x1 * x1 + x2 * x2;
#pragma unroll
        for (int m = 32; m >= 1; m >>= 1) ss += __shfl_xor(ss, m, 64);
        float r = 1.0f / sqrtf(ss * (1.0f / 128.0f) + EPS);
        x1 *= r; x2 *= r;
        p[lane]      = f2bf(x1 * c + x2 * s);
        p[lane + 64] = f2bf(x2 * c - x1 * s);
    }
    unsigned short* pv = qkv + rowbase + (size_t)2 * HDIM_;
    const float* pe = ve + (size_t)(b * T_ + t) * HDIM_ + (size_t)h * D_;
    pv[lane]      = f2bf(l0 * bf2f(pv[lane])      + l1 * pe[lane]);
    pv[lane + 64] = f2bf(l0 * bf2f(pv[lane + 64]) + l1 * pe[lane + 64]);
}

// ---------------------------------------------------------------------------
// MFMA flash attention (bf16, f32 accum). Block = 256 thr = 4 waves, one
// (b,h,qtile=64); wave w owns q-rows [q0+16w, +16). KV tiles of 64.
// Swapped QK^T: S^T = mfma(K_frag, Q_frag) -> lane holds 4 kv-rows x 1 q-col.
// K in LDS swizzled via pre-swizzled global_load_lds; V transposed in LDS
// (Vt[d][kv], swizzled); P routed through per-wave swizzled LDS Pt[q][kv].
// ---------------------------------------------------------------------------
__global__ __launch_bounds__(256) void attn_mfma(
    const unsigned short* __restrict__ qkv, unsigned short* __restrict__ y) {
    __shared__ __align__(16) unsigned short Ks[64 * 128];   // [kv][d] 16KB
    __shared__ __align__(16) unsigned short Vt[128 * 64];   // [d][kv] 16KB
    __shared__ __align__(16) unsigned short Pt[4][16 * 64]; // per-wave [q][kv] 8KB

    const int tid = threadIdx.x;
    const int l = tid & 63, w = tid >> 6;
    const int g = l >> 4, q16 = l & 15;
    const int qt = gridDim.x - 1 - blockIdx.x;   // heavy tiles dispatch first
    const int h = blockIdx.y, b = blockIdx.z;
    const int q0 = qt * 64;
    const int roff = q16 & 7;

    // Q fragments: wave w, lane row q0+16w+q16, 8 contiguous d per kslice
    const int qrow = q0 + w * 16 + q16;
    const size_t qbase = ((size_t)(b * T_ + qrow) * 3) * HDIM_ + (size_t)h * D_;
    bf16x8 qf[4];
#pragma unroll
    for (int ks = 0; ks < 4; ++ks)
        qf[ks] = *(const bf16x8*)&qkv[qbase + ks * 32 + g * 8];

    f32x4 accO[8];
#pragma unroll
    for (int i = 0; i < 8; ++i) accO[i] = (f32x4){0.f, 0.f, 0.f, 0.f};
    float m_s = -1e30f, l_s = 0.f;

    const int nkv = qt + 1;
    for (int it = 0; it < nkv; ++it) {
        const int kv0 = it * 64;
        // ---- stage K via global_load_lds (pre-swizzled source) ----
#pragma unroll
        for (int i = 0; i < 4; ++i) {
            int rloc = (w * 4 + i) * 4 + g;           // local kv row (per lane)
            int chunk = q16 ^ (rloc & 7);
            const unsigned short* src =
                &qkv[((size_t)(b * T_ + kv0 + rloc) * 3 + 1) * HDIM_ +
                     (size_t)h * D_ + chunk * 8];
            async_ld16(&Ks[(w * 4 + i) * 512], src);
        }
        // ---- stage V transposed: Vt[d][kv], swizzle kv ^= (d&7)<<3 ----
        // 64 kv x 128 d = 1024 ushort8 units; 256 threads x 4 iters.
#pragma unroll
        for (int u = 0; u < 4; ++u) {
            int unit = tid + u * 256;
            int kvr = unit & 63, dc = unit >> 6;      // dc in 0..15
            ushort8 vv = *(const ushort8*)&qkv[((size_t)(b * T_ + kv0 + kvr) * 3 + 2) * HDIM_ +
                                               (size_t)h * D_ + dc * 8];
#pragma unroll
            for (int j = 0; j < 8; ++j)
                Vt[(dc * 8 + j) * 64 + (kvr ^ (j << 3))] = vv[j];
        }
        __syncthreads();

        // ---- S^T = K * Q^T (16 MFMA) ----
        f32x4 st[4];
#pragma unroll
        for (int fk = 0; fk < 4; ++fk) {
            f32x4 a = (f32x4){0.f, 0.f, 0.f, 0.f};
            int row = fk * 16 + q16;
#pragma unroll
            for (int ks = 0; ks < 4; ++ks) {
                bf16x8 kf = *(const bf16x8*)&Ks[row * 128 +
                                                ((ks * 32 + g * 8) ^ (roff << 3))];
                a = __builtin_amdgcn_mfma_f32_16x16x32_bf16(kf, qf[ks], a, 0, 0, 0);
            }
            st[fk] = a;
        }

        // ---- online softmax over kv (per q-col = q16) ----
        float sv[4][4];
        float pmax = -1e30f;
        const bool edge = (kv0 + 64 > q0);
#pragma unroll
        for (int fk = 0; fk < 4; ++fk)
#pragma unroll
            for (int r = 0; r < 4; ++r) {
                float sc_ = st[fk][r] * ATTN_SCALE;
                if (edge) {
                    int kvg = kv0 + fk * 16 + 4 * g + r;
                    if (kvg > qrow) sc_ = -1e30f;
                }
                sv[fk][r] = sc_;
                pmax = fmaxf(pmax, sc_);
            }
        pmax = fmaxf(pmax, __shfl_xor(pmax, 16));
        pmax = fmaxf(pmax, __shfl_xor(pmax, 32));
        float mnew = fmaxf(m_s, pmax);
        float scl = __expf(m_s - mnew);
        m_s = mnew;
        float rsum = 0.f;
#pragma unroll
        for (int fk = 0; fk < 4; ++fk)
#pragma unroll
            for (int r = 0; r < 4; ++r) {
                sv[fk][r] = __expf(sv[fk][r] - mnew);
                rsum += sv[fk][r];
            }
        rsum += __shfl_xor(rsum, 16);
        rsum += __shfl_xor(rsum, 32);
        l_s = l_s * scl + rsum;

        // ---- pack P -> per-wave LDS (bf16, swizzled) ----
#pragma unroll
        for (int fk = 0; fk < 4; ++fk)
#pragma unroll
            for (int rp = 0; rp < 2; ++rp) {
                unsigned pk = ((unsigned)f2bf(sv[fk][2 * rp + 1]) << 16) |
                              (unsigned)f2bf(sv[fk][2 * rp]);
                int kv = fk * 16 + 4 * g + 2 * rp;
                *(unsigned*)&Pt[w][q16 * 64 + (kv ^ (roff << 3))] = pk;
            }

        // ---- rescale O by per-row scale (rows = 4g+r live in lane regs) ----
        f32x4 scv;
        scv[0] = __shfl(scl, 4 * g + 0);
        scv[1] = __shfl(scl, 4 * g + 1);
        scv[2] = __shfl(scl, 4 * g + 2);
        scv[3] = __shfl(scl, 4 * g + 3);
#pragma unroll
        for (int fo = 0; fo < 8; ++fo) accO[fo] *= scv;

        // ---- PV: O += P * V (16 MFMA) ----
        bf16x8 pa[2];
#pragma unroll
        for (int ks = 0; ks < 2; ++ks)
            pa[ks] = *(const bf16x8*)&Pt[w][q16 * 64 + ((ks * 32 + g * 8) ^ (roff << 3))];
#pragma unroll
        for (int fo = 0; fo < 8; ++fo) {
            int drow = fo * 16 + q16;
#pragma unroll
            for (int ks = 0; ks < 2; ++ks) {
                bf16x8 vf = *(const bf16x8*)&Vt[drow * 64 +
                                                ((ks * 32 + g * 8) ^ (roff << 3))];
                accO[fo] = __builtin_amdgcn_mfma_f32_16x16x32_bf16(pa[ks], vf, accO[fo], 0, 0, 0);
            }
        }
        __syncthreads();
    }

    // ---- epilogue: y[b, t, h*128 + d] = O / l ----
    float inv = 1.0f / l_s;
    f32x4 iv;
    iv[0] = __shfl(inv, 4 * g + 0);
    iv[1] = __shfl(inv, 4 * g + 1);
    iv[2] = __shfl(inv, 4 * g + 2);
    iv[3] = __shfl(inv, 4 * g + 3);
#pragma unroll
    for (int r = 0; r < 4; ++r) {
        size_t yb = ((size_t)(b * T_ + q0 + w * 16 + 4 * g + r)) * HDIM_ +
                    (size_t)h * D_ + q16;
#pragma unroll
        for (int fo = 0; fo < 8; ++fo)
            y[yb + fo * 16] = f2bf(accO[fo][r] * iv[r]);
    }
}

// ---------------------------------------------------------------------------
// Workspace (bytes):
//   qkv bf16  [0,   48M)   y bf16 [48M, 64M)   xb [64M, 80M)
//   wb  [80M, 86M)  pb [86M, 88M)  cos/sin f32 [88M, 88.5M)
// ---------------------------------------------------------------------------
extern "C" void kernel_launch(void* const* d_in, const int* in_sizes, int n_in,
                              void* d_out, int out_size, void* d_ws, size_t ws_size,
                              hipStream_t stream) {
    (void)in_sizes; (void)n_in; (void)out_size; (void)ws_size;
    const float* x        = (const float*)d_in[0];
    const float* ve       = (const float*)d_in[1];
    const float* qkv_w    = (const float*)d_in[2];
    const float* lambdas  = (const float*)d_in[3];
    const float* c_proj_w = (const float*)d_in[4];
    float* out = (float*)d_out;

    char* ws = (char*)d_ws;
    unsigned short* qkv = (unsigned short*)ws;                             // 8192*3072
    unsigned short* y   = (unsigned short*)(ws + 50331648);                // 8192*1024
    unsigned short* xb  = (unsigned short*)(ws + 67108864);                // 8192*1024
    unsigned short* wb  = (unsigned short*)(ws + 83886080);                // 3072*1024
    unsigned short* pb  = (unsigned short*)(ws + 90177536);                // 1024*1024
    float* cost = (float*)(ws + 92274688);                                 // 2048*32
    float* sint = cost + T_ * 32;

    hipLaunchKernelGGL(cvtk, dim3(8192), dim3(256), 0, stream, x, xb, 8192 * 1024 / 4);
    hipLaunchKernelGGL(cvtk, dim3(3072), dim3(256), 0, stream, qkv_w, wb, 3072 * 1024 / 4);
    hipLaunchKernelGGL(cvtk, dim3(1024), dim3(256), 0, stream, c_proj_w, pb, 1024 * 1024 / 4);
    hipLaunchKernelGGL(rope_tables_k, dim3(256), dim3(256), 0, stream, cost, sint);

    hipLaunchKernelGGL(gemm_bf16_nt, dim3(24, 64), dim3(256), 0, stream,
                       xb, wb, (float*)nullptr, qkv, B_ * T_, 3 * HDIM_, DIM_);
    hipLaunchKernelGGL(qkv_prep_k, dim3(B_ * T_ * H_ / 4), dim3(256), 0, stream,
                       qkv, ve, lambdas, cost, sint);
    hipLaunchKernelGGL(attn_mfma, dim3(T_ / 64, H_, B_), dim3(256), 0, stream, qkv, y);
    hipLaunchKernelGGL(gemm_bf16_nt, dim3(8, 64), dim3(256), 0, stream,
                       y, pb, out, (unsigned short*)nullptr, B_ * T_, DIM_, HDIM_);
}

// Round 4
// 333.632 us; speedup vs baseline: 5.9661x; 1.2579x over previous
//
#include <hip/hip_runtime.h>
#include <hip/hip_bf16.h>

constexpr int B_ = 4;
constexpr int T_ = 2048;
constexpr int DIM_ = 1024;
constexpr int H_ = 8;
constexpr int D_ = 128;
constexpr int HDIM_ = H_ * D_;   // 1024

typedef __attribute__((ext_vector_type(8))) short bf16x8;
typedef __attribute__((ext_vector_type(8))) unsigned short ushort8;
typedef __attribute__((ext_vector_type(4))) float f32x4;

#define ATTN_SCALE 0.08838834764831845f

__device__ __forceinline__ unsigned short f2bf(float x) {
    unsigned u = __float_as_uint(x);
    unsigned r = (u + 0x7FFFu + ((u >> 16) & 1u)) >> 16;
    return (unsigned short)r;
}
__device__ __forceinline__ float bf2f(unsigned short u) {
    return __uint_as_float(((unsigned)u) << 16);
}

// async 16B global -> LDS (dest: wave-uniform base + lane*16; src: per-lane)
__device__ __forceinline__ void async_ld16(void* ldsdst, const void* gsrc) {
    __builtin_amdgcn_global_load_lds(
        (const __attribute__((address_space(1))) unsigned int*)gsrc,
        (__attribute__((address_space(3))) unsigned int*)ldsdst, 16, 0, 0);
}

// ---------------------------------------------------------------------------
// f32 -> bf16 convert, 4 elems/thread
// ---------------------------------------------------------------------------
__global__ __launch_bounds__(256) void cvtk(const float* __restrict__ in,
                                            unsigned short* __restrict__ out, int n4) {
    int i = blockIdx.x * 256 + threadIdx.x;
    if (i < n4) {
        float4 v = ((const float4*)in)[i];
        ushort4 o;
        o.x = f2bf(v.x); o.y = f2bf(v.y); o.z = f2bf(v.z); o.w = f2bf(v.w);
        ((ushort4*)out)[i] = o;
    }
}

// ---------------------------------------------------------------------------
// RoPE tables (f32): cos/sin[t][j], j<32 real freqs; j>=32 identity.
// freq = (1/1024)^(j/31), theta = t*freq.
// ---------------------------------------------------------------------------
__global__ void rope_tables_k(float* __restrict__ cost, float* __restrict__ sint) {
    int idx = blockIdx.x * blockDim.x + threadIdx.x;
    if (idx >= T_ * 32) return;
    int t = idx >> 5, j = idx & 31;
    float e = (float)j * (1.0f / 31.0f);
    float freq = powf(1.0f / 1024.0f, e);
    float th = (float)t * freq;
    cost[idx] = cosf(th);
    sint[idx] = sinf(th);
}

// ---------------------------------------------------------------------------
// bf16 NT GEMM: C[M,N] = A[M,K] * B[N,K]^T, 128x128 tile, BK=64, 4 waves 2x2,
// each wave 64x64 out (4x4 frags of 16x16x32 MFMA). global_load_lds staging
// with pre-swizzled source; LDS[row][c] = G[row][c ^ (row&7)] (16B chunks).
// C written f32 (Cf) or bf16 (Cb) -- exactly one non-null.
// ---------------------------------------------------------------------------
__global__ __launch_bounds__(256) void gemm_bf16_nt(
    const unsigned short* __restrict__ A, const unsigned short* __restrict__ Bw,
    float* __restrict__ Cf, unsigned short* __restrict__ Cb,
    int M, int N, int K) {
    __shared__ __align__(16) unsigned short As[128 * 64];
    __shared__ __align__(16) unsigned short Bs[128 * 64];
    const int tid = threadIdx.x;
    const int l = tid & 63, w = tid >> 6;
    const int g = l >> 4, q16 = l & 15;

    // bijective XCD swizzle (nwg % 8 == 0 for all our grids)
    int nwg = gridDim.x * gridDim.y;
    int lin = blockIdx.y * gridDim.x + blockIdx.x;
    int swz = (lin & 7) * (nwg >> 3) + (lin >> 3);
    int bx = swz % gridDim.x, by = swz / gridDim.x;
    const size_t m0 = (size_t)by * 128, n0 = (size_t)bx * 128;
    const int wm = (w >> 1) * 64, wn = (w & 1) * 64;

    f32x4 acc[4][4];
#pragma unroll
    for (int i = 0; i < 4; ++i)
#pragma unroll
        for (int j = 0; j < 4; ++j) acc[i][j] = (f32x4){0.f, 0.f, 0.f, 0.f};

    const int srow = l >> 3;                   // 0..7 within 8-row group
    const int schunk = (l & 7) ^ (srow & 7);   // pre-swizzled source chunk
    const unsigned short* aBase = A + (m0 + srow) * (size_t)K + schunk * 8;
    const unsigned short* bBase = Bw + (n0 + srow) * (size_t)K + schunk * 8;
    const int roff = q16 & 7;                  // read-row swizzle key

    for (int k0 = 0; k0 < K; k0 += 64) {
#pragma unroll
        for (int i = 0; i < 4; ++i) {
            size_t rstep = (size_t)(w * 4 + i) * 8 * K;
            async_ld16(&As[(w * 4 + i) * 512], aBase + rstep + k0);
            async_ld16(&Bs[(w * 4 + i) * 512], bBase + rstep + k0);
        }
        __syncthreads();
        __builtin_amdgcn_s_setprio(1);
#pragma unroll
        for (int ks = 0; ks < 2; ++ks) {
            bf16x8 af[4], bf[4];
#pragma unroll
            for (int f = 0; f < 4; ++f) {
                int off = (ks * 32 + g * 8) ^ (roff << 3);
                af[f] = *(const bf16x8*)&As[(wm + f * 16 + q16) * 64 + off];
                bf[f] = *(const bf16x8*)&Bs[(wn + f * 16 + q16) * 64 + off];
            }
#pragma unroll
            for (int fm = 0; fm < 4; ++fm)
#pragma unroll
                for (int fn = 0; fn < 4; ++fn)
                    acc[fm][fn] = __builtin_amdgcn_mfma_f32_16x16x32_bf16(
                        af[fm], bf[fn], acc[fm][fn], 0, 0, 0);
        }
        __builtin_amdgcn_s_setprio(0);
        __syncthreads();
    }

    if (Cb) {
#pragma unroll
        for (int fm = 0; fm < 4; ++fm)
#pragma unroll
            for (int r = 0; r < 4; ++r) {
                size_t base = (m0 + wm + fm * 16 + 4 * g + r) * (size_t)N + n0 + wn + q16;
#pragma unroll
                for (int fn = 0; fn < 4; ++fn)
                    Cb[base + fn * 16] = f2bf(acc[fm][fn][r]);
            }
    } else {
#pragma unroll
        for (int fm = 0; fm < 4; ++fm)
#pragma unroll
            for (int r = 0; r < 4; ++r) {
                size_t base = (m0 + wm + fm * 16 + 4 * g + r) * (size_t)N + n0 + wn + q16;
#pragma unroll
                for (int fn = 0; fn < 4; ++fn)
                    Cf[base + fn * 16] = acc[fm][fn][r];
            }
    }
}

// ---------------------------------------------------------------------------
// Pointwise prep on q,k only (in-place, bf16 qkv, layout B,T,3,H,D):
//   RMSNorm over D then RoPE. One wave per (b,t,h); lane l owns d=l, l+64.
// ---------------------------------------------------------------------------
__global__ __launch_bounds__(256) void qkv_prep_k(
    unsigned short* __restrict__ qkv,
    const float* __restrict__ cost, const float* __restrict__ sint) {
    const int gw = (blockIdx.x * 256 + threadIdx.x) >> 6;
    const int lane = threadIdx.x & 63;
    const int h = gw & (H_ - 1);
    const int t = (gw / H_) & (T_ - 1);
    const int b = gw / (H_ * T_);
    const size_t rowbase = ((size_t)(b * T_ + t) * 3) * HDIM_ + (size_t)h * D_;
    const float c = (lane < 32) ? cost[t * 32 + lane] : 1.0f;
    const float s = (lane < 32) ? sint[t * 32 + lane] : 0.0f;
    const float EPS = 1.1920928955078125e-07f;

#pragma unroll
    for (int qk = 0; qk < 2; ++qk) {
        unsigned short* p = qkv + rowbase + (size_t)qk * HDIM_;
        float x1 = bf2f(p[lane]), x2 = bf2f(p[lane + 64]);
        float ss = x1 * x1 + x2 * x2;
#pragma unroll
        for (int m = 32; m >= 1; m >>= 1) ss += __shfl_xor(ss, m, 64);
        float r = 1.0f / sqrtf(ss * (1.0f / 128.0f) + EPS);
        x1 *= r; x2 *= r;
        p[lane]      = f2bf(x1 * c + x2 * s);
        p[lane + 64] = f2bf(x2 * c - x1 * s);
    }
}

// ---------------------------------------------------------------------------
// V blend + transpose: vT[b][h][d][t] = lambdas[0]*v + lambdas[1]*ve.
// 64x64 LDS tile, pad 65; coalesced ushort8 load and store.
// Grid (2 d-tiles, 32 t-tiles, 32 (b,h)).
// ---------------------------------------------------------------------------
__global__ __launch_bounds__(256) void vtrans_k(
    const unsigned short* __restrict__ qkv, const float* __restrict__ ve,
    const float* __restrict__ lambdas, unsigned short* __restrict__ vT) {
    __shared__ unsigned short lds[64][65];
    const int tid = threadIdx.x;
    const int d0 = blockIdx.x * 64, t0 = blockIdx.y * 64;
    const int p = blockIdx.z;
    const int h = p & 7, b = p >> 3;
    const float l0 = lambdas[0], l1 = lambdas[1];

#pragma unroll
    for (int u = 0; u < 2; ++u) {
        int unit = tid + u * 256;
        int i = unit >> 3, jc = (unit & 7) * 8;
        size_t row = (size_t)(b * T_ + t0 + i);
        ushort8 vv = *(const ushort8*)&qkv[(row * 3 + 2) * HDIM_ + h * D_ + d0 + jc];
        const float* pe = &ve[row * HDIM_ + h * D_ + d0 + jc];
        float4 e0 = *(const float4*)pe;
        float4 e1 = *(const float4*)(pe + 4);
        lds[i][jc + 0] = f2bf(l0 * bf2f(vv[0]) + l1 * e0.x);
        lds[i][jc + 1] = f2bf(l0 * bf2f(vv[1]) + l1 * e0.y);
        lds[i][jc + 2] = f2bf(l0 * bf2f(vv[2]) + l1 * e0.z);
        lds[i][jc + 3] = f2bf(l0 * bf2f(vv[3]) + l1 * e0.w);
        lds[i][jc + 4] = f2bf(l0 * bf2f(vv[4]) + l1 * e1.x);
        lds[i][jc + 5] = f2bf(l0 * bf2f(vv[5]) + l1 * e1.y);
        lds[i][jc + 6] = f2bf(l0 * bf2f(vv[6]) + l1 * e1.z);
        lds[i][jc + 7] = f2bf(l0 * bf2f(vv[7]) + l1 * e1.w);
    }
    __syncthreads();
#pragma unroll
    for (int u = 0; u < 2; ++u) {
        int unit = tid + u * 256;
        int r = unit >> 3, tc = (unit & 7) * 8;
        ushort8 o;
#pragma unroll
        for (int m = 0; m < 8; ++m) o[m] = lds[tc + m][r];
        *(ushort8*)&vT[((size_t)(b * H_ + h) * D_ + d0 + r) * T_ + t0 + tc] = o;
    }
}

// ---------------------------------------------------------------------------
// MFMA flash attention (bf16, f32 accum). 256 thr = 4 waves per block; one
// (b,h,qtile=64); wave w owns q-rows [q0+16w,+16). KV tiles of 64.
// Swapped QK^T: S^T = mfma(K,Q). K staged from qkv, V staged from vT
// (pre-transposed), both via pre-swizzled global_load_lds. P via per-wave
// swizzled LDS. 1D grid with XCD clustering: each XCD owns 4 (b,h) pairs.
// ---------------------------------------------------------------------------
__global__ __launch_bounds__(256) void attn_mfma(
    const unsigned short* __restrict__ qkv, const unsigned short* __restrict__ vT,
    unsigned short* __restrict__ y) {
    __shared__ __align__(16) unsigned short Ks[64 * 128];   // [kv][d] 16KB
    __shared__ __align__(16) unsigned short Vs[128 * 64];   // [d][kv] 16KB
    __shared__ __align__(16) unsigned short Pt[4][16 * 64]; // per-wave [q][kv] 8KB

    const int tid = threadIdx.x;
    const int l = tid & 63, w = tid >> 6;
    const int g = l >> 4, q16 = l & 15;
    // XCD-clustered decode: xcd owns pairs {xcd, xcd+8, xcd+16, xcd+24}
    const int bid = blockIdx.x;
    const int xcd = bid & 7, slot = bid >> 3;
    const int pord = slot >> 5, qo = slot & 31;
    const int p = pord * 8 + xcd;
    const int h = p & 7, b = p >> 3;
    const int qt = 31 - qo;                     // heavy tiles first
    const int q0 = qt * 64;
    const int roff = q16 & 7;

    // Q fragments: wave w, lane row q0+16w+q16, 8 contiguous d per kslice
    const int qrow = q0 + w * 16 + q16;
    const size_t qbase = ((size_t)(b * T_ + qrow) * 3) * HDIM_ + (size_t)h * D_;
    bf16x8 qf[4];
#pragma unroll
    for (int ks = 0; ks < 4; ++ks)
        qf[ks] = *(const bf16x8*)&qkv[qbase + ks * 32 + g * 8];

    f32x4 accO[8];
#pragma unroll
    for (int i = 0; i < 8; ++i) accO[i] = (f32x4){0.f, 0.f, 0.f, 0.f};
    float m_s = -1e30f, l_s = 0.f;

    const int nkv = qt + 1;
    for (int it = 0; it < nkv; ++it) {
        const int kv0 = it * 64;
        __syncthreads();   // all waves done reading Ks/Vs from prev iter
        // ---- stage K [64 kv][128 d] via global_load_lds, pre-swizzled ----
#pragma unroll
        for (int i = 0; i < 4; ++i) {
            int rloc = (w * 4 + i) * 4 + g;           // kv row (per lane)
            int chunk = q16 ^ (rloc & 7);
            const unsigned short* src =
                &qkv[((size_t)(b * T_ + kv0 + rloc) * 3 + 1) * HDIM_ +
                     (size_t)h * D_ + chunk * 8];
            async_ld16(&Ks[(w * 4 + i) * 512], src);
        }
        // ---- stage V [128 d][64 kv] from vT via global_load_lds ----
#pragma unroll
        for (int i = 0; i < 4; ++i) {
            int rloc = (w * 4 + i) * 8 + (l >> 3);    // d row (per lane)
            int chunk = (l & 7) ^ (rloc & 7);
            const unsigned short* src =
                &vT[((size_t)(b * H_ + h) * D_ + rloc) * T_ + kv0 + chunk * 8];
            async_ld16(&Vs[(w * 4 + i) * 512], src);
        }
        __syncthreads();

        // ---- S^T = K * Q^T (16 MFMA) ----
        f32x4 st[4];
        __builtin_amdgcn_s_setprio(1);
#pragma unroll
        for (int fk = 0; fk < 4; ++fk) {
            f32x4 a = (f32x4){0.f, 0.f, 0.f, 0.f};
            int row = fk * 16 + q16;
#pragma unroll
            for (int ks = 0; ks < 4; ++ks) {
                bf16x8 kf = *(const bf16x8*)&Ks[row * 128 +
                                                ((ks * 32 + g * 8) ^ (roff << 3))];
                a = __builtin_amdgcn_mfma_f32_16x16x32_bf16(kf, qf[ks], a, 0, 0, 0);
            }
            st[fk] = a;
        }
        __builtin_amdgcn_s_setprio(0);

        // ---- online softmax over kv (per q-col = q16) ----
        float sv[4][4];
        float pmax = -1e30f;
        const bool edge = (kv0 + 64 > q0);
#pragma unroll
        for (int fk = 0; fk < 4; ++fk)
#pragma unroll
            for (int r = 0; r < 4; ++r) {
                float sc_ = st[fk][r] * ATTN_SCALE;
                if (edge) {
                    int kvg = kv0 + fk * 16 + 4 * g + r;
                    if (kvg > qrow) sc_ = -1e30f;
                }
                sv[fk][r] = sc_;
                pmax = fmaxf(pmax, sc_);
            }
        pmax = fmaxf(pmax, __shfl_xor(pmax, 16));
        pmax = fmaxf(pmax, __shfl_xor(pmax, 32));
        float mnew = fmaxf(m_s, pmax);
        float scl = __expf(m_s - mnew);
        m_s = mnew;
        float rsum = 0.f;
#pragma unroll
        for (int fk = 0; fk < 4; ++fk)
#pragma unroll
            for (int r = 0; r < 4; ++r) {
                sv[fk][r] = __expf(sv[fk][r] - mnew);
                rsum += sv[fk][r];
            }
        rsum += __shfl_xor(rsum, 16);
        rsum += __shfl_xor(rsum, 32);
        l_s = l_s * scl + rsum;

        // ---- pack P -> per-wave LDS (bf16, swizzled) ----
#pragma unroll
        for (int fk = 0; fk < 4; ++fk)
#pragma unroll
            for (int rp = 0; rp < 2; ++rp) {
                unsigned pk = ((unsigned)f2bf(sv[fk][2 * rp + 1]) << 16) |
                              (unsigned)f2bf(sv[fk][2 * rp]);
                int kv = fk * 16 + 4 * g + 2 * rp;
                *(unsigned*)&Pt[w][q16 * 64 + (kv ^ (roff << 3))] = pk;
            }

        // ---- rescale O (rows 4g+r live across lanes) ----
        f32x4 scv;
        scv[0] = __shfl(scl, 4 * g + 0);
        scv[1] = __shfl(scl, 4 * g + 1);
        scv[2] = __shfl(scl, 4 * g + 2);
        scv[3] = __shfl(scl, 4 * g + 3);
#pragma unroll
        for (int fo = 0; fo < 8; ++fo) accO[fo] *= scv;

        // ---- PV: O += P * V (16 MFMA) ----
        bf16x8 pa[2];
#pragma unroll
        for (int ks = 0; ks < 2; ++ks)
            pa[ks] = *(const bf16x8*)&Pt[w][q16 * 64 + ((ks * 32 + g * 8) ^ (roff << 3))];
        __builtin_amdgcn_s_setprio(1);
#pragma unroll
        for (int fo = 0; fo < 8; ++fo) {
            int drow = fo * 16 + q16;
#pragma unroll
            for (int ks = 0; ks < 2; ++ks) {
                bf16x8 vf = *(const bf16x8*)&Vs[drow * 64 +
                                                ((ks * 32 + g * 8) ^ (roff << 3))];
                accO[fo] = __builtin_amdgcn_mfma_f32_16x16x32_bf16(pa[ks], vf, accO[fo], 0, 0, 0);
            }
        }
        __builtin_amdgcn_s_setprio(0);
    }

    // ---- epilogue: y[b, t, h*128 + d] = O / l ----
    float inv = 1.0f / l_s;
    f32x4 iv;
    iv[0] = __shfl(inv, 4 * g + 0);
    iv[1] = __shfl(inv, 4 * g + 1);
    iv[2] = __shfl(inv, 4 * g + 2);
    iv[3] = __shfl(inv, 4 * g + 3);
#pragma unroll
    for (int r = 0; r < 4; ++r) {
        size_t yb = ((size_t)(b * T_ + q0 + w * 16 + 4 * g + r)) * HDIM_ +
                    (size_t)h * D_ + q16;
#pragma unroll
        for (int fo = 0; fo < 8; ++fo)
            y[yb + fo * 16] = f2bf(accO[fo][r] * iv[r]);
    }
}

// ---------------------------------------------------------------------------
// Workspace (bytes):
//   qkv bf16 [0,48M)  y [48M,64M)  xb [64M,80M)  wb [80M,86M)  pb [86M,88M)
//   cos/sin f32 [88M,88.5M)  vT bf16 [96M,112M)
// ---------------------------------------------------------------------------
extern "C" void kernel_launch(void* const* d_in, const int* in_sizes, int n_in,
                              void* d_out, int out_size, void* d_ws, size_t ws_size,
                              hipStream_t stream) {
    (void)in_sizes; (void)n_in; (void)out_size; (void)ws_size;
    const float* x        = (const float*)d_in[0];
    const float* ve       = (const float*)d_in[1];
    const float* qkv_w    = (const float*)d_in[2];
    const float* lambdas  = (const float*)d_in[3];
    const float* c_proj_w = (const float*)d_in[4];
    float* out = (float*)d_out;

    char* ws = (char*)d_ws;
    unsigned short* qkv = (unsigned short*)ws;                             // 8192*3072
    unsigned short* y   = (unsigned short*)(ws + 50331648);                // 8192*1024
    unsigned short* xb  = (unsigned short*)(ws + 67108864);                // 8192*1024
    unsigned short* wb  = (unsigned short*)(ws + 83886080);                // 3072*1024
    unsigned short* pb  = (unsigned short*)(ws + 90177536);                // 1024*1024
    float* cost = (float*)(ws + 92274688);                                 // 2048*32
    float* sint = cost + T_ * 32;
    unsigned short* vT  = (unsigned short*)(ws + 100663296);               // 32*128*2048

    hipLaunchKernelGGL(cvtk, dim3(8192), dim3(256), 0, stream, x, xb, 8192 * 1024 / 4);
    hipLaunchKernelGGL(cvtk, dim3(3072), dim3(256), 0, stream, qkv_w, wb, 3072 * 1024 / 4);
    hipLaunchKernelGGL(cvtk, dim3(1024), dim3(256), 0, stream, c_proj_w, pb, 1024 * 1024 / 4);
    hipLaunchKernelGGL(rope_tables_k, dim3(256), dim3(256), 0, stream, cost, sint);

    hipLaunchKernelGGL(gemm_bf16_nt, dim3(24, 64), dim3(256), 0, stream,
                       xb, wb, (float*)nullptr, qkv, B_ * T_, 3 * HDIM_, DIM_);
    hipLaunchKernelGGL(qkv_prep_k, dim3(B_ * T_ * H_ / 4), dim3(256), 0, stream,
                       qkv, cost, sint);
    hipLaunchKernelGGL(vtrans_k, dim3(2, 32, 32), dim3(256), 0, stream,
                       qkv, ve, lambdas, vT);
    hipLaunchKernelGGL(attn_mfma, dim3(1024), dim3(256), 0, stream, qkv, vT, y);
    hipLaunchKernelGGL(gemm_bf16_nt, dim3(8, 64), dim3(256), 0, stream,
                       y, pb, out, (unsigned short*)nullptr, B_ * T_, DIM_, HDIM_);
}